// Round 1
// baseline (1083.140 us; speedup 1.0000x reference)
//
#include <hip/hip_runtime.h>
#include <hip/hip_bf16.h>

#define BB 128
#define LL 200
#define DD 512
#define HH 8
#define DK 64
#define NBLK 2
#define BL (BB*LL)
#define LLP 224   // padded key length for V^T rows (16B-aligned, zero tail)

typedef unsigned short ushort_t;
typedef unsigned int uint_t;
typedef __attribute__((ext_vector_type(8))) short short8;
typedef __attribute__((ext_vector_type(4))) short short4v;
typedef __attribute__((ext_vector_type(4))) float f32x4;

__device__ inline ushort_t f2b(float x) {
    unsigned u = __float_as_uint(x);
    unsigned r = (u + 0x7FFF + ((u >> 16) & 1)) >> 16;
    return (ushort_t)r;
}

__device__ inline void gload16(const void* g, void* l) {
    __builtin_amdgcn_global_load_lds((const __attribute__((address_space(1))) void*)g,
                                     (__attribute__((address_space(3))) void*)l,
                                     16, 0, 0);
}

// ---------------- masks (keepf, kmf) ----------------
__global__ __launch_bounds__(256) void mask_kernel(const int* __restrict__ logs,
                                                   const int* __restrict__ entire,
                                                   float* __restrict__ keepf,
                                                   float* __restrict__ kmf) {
    int i = blockIdx.x * 256 + threadIdx.x;
    if (i < BL) {
        keepf[i] = (logs[i] == 0) ? 0.f : 1.f;
        kmf[i] = (logs[i] == 0 && entire[i] != 0) ? 1.f : 0.f;
    }
}

// zero the key-tail (keys 200..223) of V^T once; gemm_qkv only writes keys<200
__global__ __launch_bounds__(256) void vtail_kernel(ushort_t* __restrict__ vt) {
    int i = blockIdx.x * 256 + threadIdx.x;
    if (i < BB * HH * DK * 6) {
        int row = i / 6, c = i - 6 * row;
        *(unsigned long long*)(vt + (size_t)row * LLP + LL + c * 4) = 0ULL;
    }
}

// fused: tgt = emb*keep (fp32) ; srcb = bf16(emb*tl) — one emb read
__global__ __launch_bounds__(256) void prep_kernel(const int* __restrict__ logs,
                                                   const float* __restrict__ emb,
                                                   float* __restrict__ tgt,
                                                   ushort_t* __restrict__ srcb) {
    int row = blockIdx.x;
    int t = threadIdx.x;
    bool src = (logs[row] == 0);
    float kf = src ? 0.f : 1.f, sf = src ? 1.f : 0.f;
    size_t base = (size_t)row * DD;
    float e0 = emb[base + t], e1 = emb[base + t + 256];
    tgt[base + t] = e0 * kf;
    tgt[base + t + 256] = e1 * kf;
    srcb[base + t] = f2b(e0 * sf);
    srcb[base + t + 256] = f2b(e1 * sf);
}

// fused weight transpose + bf16 for all 10 matrices: grid (16,16,10)
__global__ __launch_bounds__(256) void wtrans10_kernel(const float* __restrict__ Wq,
                                                       const float* __restrict__ Wk,
                                                       const float* __restrict__ Wv,
                                                       const float* __restrict__ W1,
                                                       const float* __restrict__ W2,
                                                       ushort_t* __restrict__ WqkvT,
                                                       ushort_t* __restrict__ W1T,
                                                       ushort_t* __restrict__ W2T) {
    __shared__ float ts[32][33];
    int tx = threadIdx.x & 31, ty = threadIdx.x >> 5;
    int bx = blockIdx.x * 32, by = blockIdx.y * 32;
    int z = blockIdx.z;
    const float* Wm;
    ushort_t* Wtm;
    if (z < 6) {
        int i = z / 3, j = z - 3 * i;
        const float* src = (j == 0) ? Wq : (j == 1) ? Wk : Wv;
        Wm = src + (size_t)i * DD * DD;
        Wtm = WqkvT + (size_t)z * DD * DD;
    } else if (z < 8) {
        Wm = W1 + (size_t)(z - 6) * DD * DD;
        Wtm = W1T + (size_t)(z - 6) * DD * DD;
    } else {
        Wm = W2 + (size_t)(z - 8) * DD * DD;
        Wtm = W2T + (size_t)(z - 8) * DD * DD;
    }
    #pragma unroll
    for (int i = 0; i < 4; i++) {
        int r = ty + i * 8;
        ts[r][tx] = Wm[(size_t)(by + r) * DD + bx + tx];
    }
    __syncthreads();
    #pragma unroll
    for (int i = 0; i < 4; i++) {
        int r = ty + i * 8;
        Wtm[(size_t)(bx + r) * DD + by + tx] = f2b(ts[tx][r]);
    }
}

// ---------------- layernorm ----------------
__global__ __launch_bounds__(256) void ln_kernel(const float* __restrict__ x,
                                                 const float* __restrict__ addx,
                                                 float* __restrict__ outf,
                                                 ushort_t* __restrict__ outb,
                                                 const float* __restrict__ g,
                                                 const float* __restrict__ bt,
                                                 const float* __restrict__ keepf) {
    int row = blockIdx.x;
    int t = threadIdx.x;
    size_t base = (size_t)row * DD;
    float v0 = x[base + t], v1 = x[base + t + 256];
    if (addx) { v0 += addx[base + t]; v1 += addx[base + t + 256]; }
    float s = v0 + v1, sq = v0 * v0 + v1 * v1;
    #pragma unroll
    for (int off = 32; off; off >>= 1) {
        s += __shfl_xor(s, off);
        sq += __shfl_xor(sq, off);
    }
    __shared__ float rs[4], rq[4];
    int wid = t >> 6, lane = t & 63;
    if (lane == 0) { rs[wid] = s; rq[wid] = sq; }
    __syncthreads();
    s = rs[0] + rs[1] + rs[2] + rs[3];
    sq = rq[0] + rq[1] + rq[2] + rq[3];
    float mean = s * (1.f / DD);
    float var = sq * (1.f / DD) - mean * mean;
    float rstd = rsqrtf(fmaxf(var, 0.f) + 1e-8f);
    float kf = keepf ? keepf[row] : 1.f;
    float o0 = ((v0 - mean) * rstd * g[t] + bt[t]) * kf;
    float o1 = ((v1 - mean) * rstd * g[t + 256] + bt[t + 256]) * kf;
    if (outf) { outf[base + t] = o0; outf[base + t + 256] = o1; }
    if (outb) { outb[base + t] = f2b(o0); outb[base + t + 256] = f2b(o1); }
}

// ---------------- bf16 MFMA GEMM, BK=64 via two 128x32 sub-tiles ----------------
// mode 1: Cb = bf16(relu(acc+bias)) ; mode 2: Cf = (Cf+acc+bias)*keepf
__global__ __launch_bounds__(256) void gemm_mfma(const ushort_t* __restrict__ A,
                                                 const ushort_t* __restrict__ Bt,
                                                 const float* __restrict__ bias,
                                                 float* __restrict__ Cf,
                                                 ushort_t* __restrict__ Cb,
                                                 const float* __restrict__ keepf,
                                                 int mode, int M, int N, int K) {
    __shared__ ushort_t sA[2][128 * 32];
    __shared__ ushort_t sB[2][128 * 32];
    int t = threadIdx.x;
    int w = t >> 6, lane = t & 63;
    int wm = w & 1, wn = w >> 1;
    int m0 = blockIdx.x * 128, n0 = blockIdx.y * 128;
    int lr = lane & 15, lq = lane >> 4;

    f32x4 acc[4][4] = {};

    for (int k0 = 0; k0 < K; k0 += 64) {
        #pragma unroll
        for (int hh = 0; hh < 2; hh++) {
            #pragma unroll
            for (int r = 0; r < 2; r++) {
                int e = (r * 256 + t) * 8;
                int row = e >> 5, col = e & 31;
                gload16(A + (size_t)(m0 + row) * K + k0 + hh * 32 + col,
                        sA[hh] + (r * 256 + w * 64) * 8);
                gload16(Bt + (size_t)(n0 + row) * K + k0 + hh * 32 + col,
                        sB[hh] + (r * 256 + w * 64) * 8);
            }
        }
        __syncthreads();

        #pragma unroll
        for (int hh = 0; hh < 2; hh++) {
            short8 af[4], bf[4];
            #pragma unroll
            for (int mt = 0; mt < 4; mt++)
                af[mt] = *(const short8*)(sA[hh] + (wm * 64 + mt * 16 + lr) * 32 + lq * 8);
            #pragma unroll
            for (int nt = 0; nt < 4; nt++)
                bf[nt] = *(const short8*)(sB[hh] + (wn * 64 + nt * 16 + lr) * 32 + lq * 8);
            #pragma unroll
            for (int mt = 0; mt < 4; mt++)
                #pragma unroll
                for (int nt = 0; nt < 4; nt++)
                    acc[mt][nt] = __builtin_amdgcn_mfma_f32_16x16x32_bf16(af[mt], bf[nt], acc[mt][nt], 0, 0, 0);
        }
        __syncthreads();
    }

    #pragma unroll
    for (int nt = 0; nt < 4; nt++) {
        int col = n0 + wn * 64 + nt * 16 + lr;
        float bv = bias[col];
        #pragma unroll
        for (int mt = 0; mt < 4; mt++) {
            int rowb = m0 + wm * 64 + mt * 16 + lq * 4;
            #pragma unroll
            for (int r = 0; r < 4; r++) {
                int row = rowb + r;
                float o = acc[mt][nt][r] + bv;
                size_t idx = (size_t)row * N + col;
                if (mode == 1) {
                    Cb[idx] = f2b(fmaxf(o, 0.f));
                } else {
                    float kf = keepf[row];
                    Cf[idx] = (Cf[idx] + o) * kf;
                }
            }
        }
    }
}

// ---------------- fused Q/K/V projection: grid (200, 4, 3), BK=64 sub-tiles ----
// z==2 (V) writes TRANSPOSED into vt[(b*8+h)*64 + d][key] (keys padded to 224),
// so attention needs no per-block V^T staging. 4 acc rows of one fragment are
// 4 consecutive keys of one d (200%4==0, rowb%4==0 -> never straddles b) => 8B store.
__global__ __launch_bounds__(256) void gemm_qkv(const ushort_t* __restrict__ Aq,
                                                const ushort_t* __restrict__ Akv,
                                                const ushort_t* __restrict__ Bqkv,
                                                const float* __restrict__ bq,
                                                const float* __restrict__ bk,
                                                const float* __restrict__ bv,
                                                ushort_t* __restrict__ qkv,
                                                ushort_t* __restrict__ vt) {
    __shared__ ushort_t sA[2][128 * 32];
    __shared__ ushort_t sB[2][128 * 32];
    int z = blockIdx.z;
    const ushort_t* A = (z == 0) ? Aq : Akv;
    const ushort_t* Bt = Bqkv + (size_t)z * DD * DD;
    const float* bias = (z == 0) ? bq : (z == 1) ? bk : bv;
    ushort_t* C = qkv + (size_t)z * BL * DD;   // used only for z<2

    int t = threadIdx.x;
    int w = t >> 6, lane = t & 63;
    int wm = w & 1, wn = w >> 1;
    int m0 = blockIdx.x * 128, n0 = blockIdx.y * 128;
    int lr = lane & 15, lq = lane >> 4;

    f32x4 acc[4][4] = {};

    for (int k0 = 0; k0 < DD; k0 += 64) {
        #pragma unroll
        for (int hh = 0; hh < 2; hh++) {
            #pragma unroll
            for (int r = 0; r < 2; r++) {
                int e = (r * 256 + t) * 8;
                int row = e >> 5, col = e & 31;
                gload16(A + (size_t)(m0 + row) * DD + k0 + hh * 32 + col,
                        sA[hh] + (r * 256 + w * 64) * 8);
                gload16(Bt + (size_t)(n0 + row) * DD + k0 + hh * 32 + col,
                        sB[hh] + (r * 256 + w * 64) * 8);
            }
        }
        __syncthreads();

        #pragma unroll
        for (int hh = 0; hh < 2; hh++) {
            short8 af[4], bf[4];
            #pragma unroll
            for (int mt = 0; mt < 4; mt++)
                af[mt] = *(const short8*)(sA[hh] + (wm * 64 + mt * 16 + lr) * 32 + lq * 8);
            #pragma unroll
            for (int nt = 0; nt < 4; nt++)
                bf[nt] = *(const short8*)(sB[hh] + (wn * 64 + nt * 16 + lr) * 32 + lq * 8);
            #pragma unroll
            for (int mt = 0; mt < 4; mt++)
                #pragma unroll
                for (int nt = 0; nt < 4; nt++)
                    acc[mt][nt] = __builtin_amdgcn_mfma_f32_16x16x32_bf16(af[mt], bf[nt], acc[mt][nt], 0, 0, 0);
        }
        __syncthreads();
    }

    #pragma unroll
    for (int nt = 0; nt < 4; nt++) {
        int col = n0 + wn * 64 + nt * 16 + lr;
        float bv2 = bias[col];
        if (z == 2) {
            int h2 = col >> 6, d2 = col & 63;
            #pragma unroll
            for (int mt = 0; mt < 4; mt++) {
                int rowb = m0 + wm * 64 + mt * 16 + lq * 4;
                int bi = rowb / LL;
                int key0 = rowb - bi * LL;
                short4v pk;
                #pragma unroll
                for (int r = 0; r < 4; r++)
                    pk[r] = (short)f2b(acc[mt][nt][r] + bv2);
                *(short4v*)(vt + ((size_t)((bi * HH + h2) * DK + d2)) * LLP + key0) = pk;
            }
        } else {
            #pragma unroll
            for (int mt = 0; mt < 4; mt++) {
                int rowb = m0 + wm * 64 + mt * 16 + lq * 4;
                #pragma unroll
                for (int r = 0; r < 4; r++) {
                    int row = rowb + r;
                    C[(size_t)row * DD + col] = f2b(acc[mt][nt][r] + bv2);
                }
            }
        }
    }
}

// ---------------- attention v6: no V staging, LDS = P only (31,744 B) ----------
// V^T comes pre-transposed from gemm_qkv (global, L2/L3-resident). LDS drops
// 61,440 -> 31,744 B: 4 blocks/CU (all 1024 blocks co-resident, was 2 rounds of 2).
// Softmax fused to one pass per qtile via per-wave-max combine:
//   tot = sum_w s_w * exp(m_w - M); barriers per qtile: 4 -> 2.
#define ATTN_LDS_BYTES 31744
__global__ __launch_bounds__(256, 4) void attn6_kernel(const ushort_t* __restrict__ q,
                                                       const ushort_t* __restrict__ k,
                                                       const ushort_t* __restrict__ vt,
                                                       const float* __restrict__ kmf,
                                                       float* __restrict__ xout) {
    extern __shared__ ushort_t su[];
    ushort_t* sP = su;                    // [64][232] bf16
    float* redm = (float*)(su + 14848);   // [256] per-wave row max
    float* reds = redm + 256;             // [256] per-wave row sum

    int t = threadIdx.x;
    int b = blockIdx.x >> 3, h = blockIdx.x & 7;
    int w = t >> 6, lane = t & 63;
    int lr = lane & 15, lq = lane >> 4;

    const ushort_t* kg = k + (size_t)b * LL * DD + h * DK;
    const ushort_t* qg = q + (size_t)b * LL * DD + h * DK;
    const ushort_t* vtg = vt + (size_t)(b * HH + h) * DK * LLP;
    float* og = xout + (size_t)b * LL * DD + h * DK;

    // K fragments + key masks hoisted across qtiles (wave w owns keys w*64..+63)
    short8 bfK[2][4];
    float km[4];
    #pragma unroll
    for (int nt = 0; nt < 4; nt++) {
        int j = w * 64 + nt * 16 + lr;
        int jc = (j < LL) ? j : (LL - 1);
        #pragma unroll
        for (int ks = 0; ks < 2; ks++)
            bfK[ks][nt] = *(const short8*)(kg + (size_t)jc * DD + ks * 32 + lq * 8);
        km[nt] = (j < LL) ? kmf[b * LL + j] : 0.f;
    }

    for (int qt = 0; qt < 4; qt++) {
        int q0 = qt * 64;

        // S = Q @ K^T ; Q frags loaded per k-slice to bound register lifetime
        f32x4 accS[4][4] = {};
        #pragma unroll
        for (int ks = 0; ks < 2; ks++) {
            short8 af[4];
            #pragma unroll
            for (int mt = 0; mt < 4; mt++) {
                int grow = q0 + mt * 16 + lr;
                if (grow > LL - 1) grow = LL - 1;
                af[mt] = *(const short8*)(qg + (size_t)grow * DD + ks * 32 + lq * 8);
            }
            #pragma unroll
            for (int nt = 0; nt < 4; nt++)
                #pragma unroll
                for (int mt = 0; mt < 4; mt++)
                    accS[mt][nt] = __builtin_amdgcn_mfma_f32_16x16x32_bf16(af[mt], bfK[ks][nt], accS[mt][nt], 0, 0, 0);
        }

        // fused: mask + scale + wave-local max + exp + wave-local sum
        float rmax[4][4];
        #pragma unroll
        for (int mt = 0; mt < 4; mt++) {
            #pragma unroll
            for (int r = 0; r < 4; r++) {
                int qrow = q0 + mt * 16 + lq * 4 + r;
                float m = -1e9f;
                #pragma unroll
                for (int nt = 0; nt < 4; nt++) {
                    int j = w * 64 + nt * 16 + lr;
                    bool ok = (j <= qrow) && (km[nt] != 0.f);
                    float s = ok ? accS[mt][nt][r] * 0.125f : -1e9f;
                    accS[mt][nt][r] = s;
                    m = fmaxf(m, s);
                }
                #pragma unroll
                for (int off = 1; off < 16; off <<= 1)
                    m = fmaxf(m, __shfl_xor(m, off));
                rmax[mt][r] = m;
                float ps = 0.f;
                #pragma unroll
                for (int nt = 0; nt < 4; nt++) {
                    float e = __expf(accS[mt][nt][r] - m);
                    accS[mt][nt][r] = e;
                    ps += e;
                }
                #pragma unroll
                for (int off = 1; off < 16; off <<= 1)
                    ps += __shfl_xor(ps, off);
                if (lr == 0) {
                    int row = mt * 16 + lq * 4 + r;
                    redm[w * 64 + row] = m;
                    reds[w * 64 + row] = ps;
                }
            }
        }
        __syncthreads();

        // combine waves: M = max_w m_w, tot = sum_w s_w*exp(m_w-M); normalize -> bf16 P
        #pragma unroll
        for (int mt = 0; mt < 4; mt++) {
            #pragma unroll
            for (int r = 0; r < 4; r++) {
                int row = mt * 16 + lq * 4 + r;
                float mw0 = redm[row], mw1 = redm[64 + row];
                float mw2 = redm[128 + row], mw3 = redm[192 + row];
                float gm = fmaxf(fmaxf(mw0, mw1), fmaxf(mw2, mw3));
                float tot = reds[row] * __expf(mw0 - gm)
                          + reds[64 + row] * __expf(mw1 - gm)
                          + reds[128 + row] * __expf(mw2 - gm)
                          + reds[192 + row] * __expf(mw3 - gm);
                // all-masked row -> gm=-1e9 -> inv=0 -> exact zeros (double masking)
                float inv = (gm < -5e8f) ? 0.f : __expf(rmax[mt][r] - gm) / tot;
                #pragma unroll
                for (int nt = 0; nt < 4; nt++) {
                    int col = w * 64 + nt * 16 + lr;
                    if (col < LLP)
                        sP[row * 232 + col] = f2b(accS[mt][nt][r] * inv);
                }
            }
        }
        __syncthreads();

        // O = P @ V ; wave w owns d-tile w*16..+15 ; V^T frags direct from global
        f32x4 accO[4] = {};
        #pragma unroll
        for (int ks2 = 0; ks2 < 7; ks2++) {
            short8 bfv = *(const short8*)(vtg + (size_t)(w * 16 + lr) * LLP + ks2 * 32 + lq * 8);
            #pragma unroll
            for (int mt = 0; mt < 4; mt++) {
                short8 afp = *(const short8*)(sP + (mt * 16 + lr) * 232 + ks2 * 32 + lq * 8);
                accO[mt] = __builtin_amdgcn_mfma_f32_16x16x32_bf16(afp, bfv, accO[mt], 0, 0, 0);
            }
        }
        #pragma unroll
        for (int mt = 0; mt < 4; mt++) {
            #pragma unroll
            for (int r = 0; r < 4; r++) {
                int row = q0 + mt * 16 + lq * 4 + r;
                if (row < LL)
                    og[(size_t)row * DD + w * 16 + lr] = accO[mt][r];
            }
        }
        // no end-of-qtile barrier needed: next qtile's redm/sP writes happen only
        // after the two barriers above, which already order them vs. these reads
    }
}

extern "C" void kernel_launch(void* const* d_in, const int* in_sizes, int n_in,
                              void* d_out, int out_size, void* d_ws, size_t ws_size,
                              hipStream_t stream) {
    const int* log_seqs = (const int*)d_in[0];
    const float* seqs_embs = (const float*)d_in[1];
    const int* entire = (const int*)d_in[2];
    const float* Wq = (const float*)d_in[3];
    const float* bq = (const float*)d_in[4];
    const float* Wk = (const float*)d_in[5];
    const float* bk = (const float*)d_in[6];
    const float* Wv = (const float*)d_in[7];
    const float* bv = (const float*)d_in[8];
    const float* lag = (const float*)d_in[9];
    const float* lab = (const float*)d_in[10];
    const float* lfg = (const float*)d_in[11];
    const float* lfb = (const float*)d_in[12];
    const float* W1 = (const float*)d_in[13];
    const float* b1 = (const float*)d_in[14];
    const float* W2 = (const float*)d_in[15];
    const float* b2 = (const float*)d_in[16];
    const float* llg = (const float*)d_in[17];
    const float* llb = (const float*)d_in[18];
    float* out = (float*)d_out;
    float* ws = (float*)d_ws;

    hipFuncSetAttribute((const void*)attn6_kernel,
                        hipFuncAttributeMaxDynamicSharedMemorySize,
                        ATTN_LDS_BYTES);

    // workspace ~245 MB (262.45 MB proven safe); vb dropped, vt (V^T, 29.4MB) added
    const size_t n = (size_t)BL * DD;
    float* tgt = ws;
    float* aout = ws + n;
    ushort_t* srcb = (ushort_t*)(ws + 2 * n);
    ushort_t* qb = srcb + n;
    ushort_t* kb = qb + n;
    ushort_t* lnb = kb + n;          // dedicated: read by gemm_qkv z=0 while z writes qb/kb/vt
    ushort_t* WqkvT = lnb + n;
    ushort_t* W1T = WqkvT + (size_t)NBLK * 3 * DD * DD;
    ushort_t* W2T = W1T + (size_t)NBLK * DD * DD;
    float* keepf = (float*)(W2T + (size_t)NBLK * DD * DD);
    float* kmf = keepf + BL;
    ushort_t* vt = (ushort_t*)(kmf + BL);   // [BB*HH*DK][LLP] bf16 V^T
    ushort_t* hb = qb;               // FFN1 out: qb dead after attention

    mask_kernel<<<(BL + 255) / 256, 256, 0, stream>>>(log_seqs, entire, keepf, kmf);
    prep_kernel<<<BL, 256, 0, stream>>>(log_seqs, seqs_embs, tgt, srcb);
    dim3 tw(16, 16, 10);
    wtrans10_kernel<<<tw, 256, 0, stream>>>(Wq, Wk, Wv, W1, W2, WqkvT, W1T, W2T);
    vtail_kernel<<<(BB * HH * DK * 6 + 255) / 256, 256, 0, stream>>>(vt);

    dim3 gg(BL / 128, DD / 128);
    dim3 gq(BL / 128, DD / 128, 3);
    for (int i = 0; i < NBLK; i++) {
        size_t wo = (size_t)i * DD * DD;
        // lnb = bf16(LN(tgt, ln_attn))
        ln_kernel<<<BL, 256, 0, stream>>>(tgt, nullptr, nullptr, lnb,
                                          lag + i * DD, lab + i * DD, nullptr);
        // fused q,k,v projections -> qb,kb (bf16) + vt (bf16, transposed)
        gemm_qkv<<<gq, 256, 0, stream>>>(lnb, srcb, WqkvT + (size_t)i * 3 * DD * DD,
                                         bq + i * DD, bk + i * DD, bv + i * DD, qb, vt);
        // attention (MFMA) -> aout fp32
        attn6_kernel<<<BB * HH, 256, ATTN_LDS_BYTES, stream>>>(qb, kb, vt, kmf, aout);
        // tgt = LN(aout (+tgt)), bf16 copy to lnb
        ln_kernel<<<BL, 256, 0, stream>>>(aout, (i == 0) ? nullptr : tgt, tgt, lnb,
                                          lfg + i * DD, lfb + i * DD, nullptr);
        // hb = bf16(relu(lnb @ W1 + b1))
        gemm_mfma<<<gg, 256, 0, stream>>>(lnb, W1T + wo, b1 + i * DD, nullptr, hb,
                                          nullptr, 1, BL, DD, DD);
        // tgt = (tgt + hb @ W2 + b2) * keep
        gemm_mfma<<<gg, 256, 0, stream>>>(hb, W2T + wo, b2 + i * DD, tgt, nullptr,
                                          keepf, 2, BL, DD, DD);
    }
    ln_kernel<<<BL, 256, 0, stream>>>(tgt, nullptr, out, nullptr, llg, llb, keepf);
}

// Round 2
// 785.513 us; speedup vs baseline: 1.3789x; 1.3789x over previous
//
#include <hip/hip_runtime.h>
#include <hip/hip_bf16.h>

#define BB 128
#define LL 200
#define DD 512
#define HH 8
#define DK 64
#define NBLK 2
#define BL (BB*LL)
#define LLP 232   // V^T key pitch (ushorts): 224 used + 8 pad; 232 gives the proven
                  // LDS bank spread AND lets global layout == LDS layout (memcpy stage)

typedef unsigned short ushort_t;
typedef unsigned int uint_t;
typedef __attribute__((ext_vector_type(8))) short short8;
typedef __attribute__((ext_vector_type(4))) short short4v;
typedef __attribute__((ext_vector_type(4))) float f32x4;

__device__ inline ushort_t f2b(float x) {
    unsigned u = __float_as_uint(x);
    unsigned r = (u + 0x7FFF + ((u >> 16) & 1)) >> 16;
    return (ushort_t)r;
}

__device__ inline void gload16(const void* g, void* l) {
    __builtin_amdgcn_global_load_lds((const __attribute__((address_space(1))) void*)g,
                                     (__attribute__((address_space(3))) void*)l,
                                     16, 0, 0);
}

// ---------------- masks (keepf, kmf) ----------------
__global__ __launch_bounds__(256) void mask_kernel(const int* __restrict__ logs,
                                                   const int* __restrict__ entire,
                                                   float* __restrict__ keepf,
                                                   float* __restrict__ kmf) {
    int i = blockIdx.x * 256 + threadIdx.x;
    if (i < BL) {
        keepf[i] = (logs[i] == 0) ? 0.f : 1.f;
        kmf[i] = (logs[i] == 0 && entire[i] != 0) ? 1.f : 0.f;
    }
}

// zero the key-tail (keys 200..231) of V^T once; gemm_qkv only writes keys<200
__global__ __launch_bounds__(256) void vtail_kernel(ushort_t* __restrict__ vt) {
    int i = blockIdx.x * 256 + threadIdx.x;
    if (i < BB * HH * DK * 8) {
        int row = i >> 3, c = i & 7;
        *(unsigned long long*)(vt + (size_t)row * LLP + LL + c * 4) = 0ULL;
    }
}

// fused: tgt = emb*keep (fp32) ; srcb = bf16(emb*tl) — one emb read
__global__ __launch_bounds__(256) void prep_kernel(const int* __restrict__ logs,
                                                   const float* __restrict__ emb,
                                                   float* __restrict__ tgt,
                                                   ushort_t* __restrict__ srcb) {
    int row = blockIdx.x;
    int t = threadIdx.x;
    bool src = (logs[row] == 0);
    float kf = src ? 0.f : 1.f, sf = src ? 1.f : 0.f;
    size_t base = (size_t)row * DD;
    float e0 = emb[base + t], e1 = emb[base + t + 256];
    tgt[base + t] = e0 * kf;
    tgt[base + t + 256] = e1 * kf;
    srcb[base + t] = f2b(e0 * sf);
    srcb[base + t + 256] = f2b(e1 * sf);
}

// fused weight transpose + bf16 for all 10 matrices: grid (16,16,10)
__global__ __launch_bounds__(256) void wtrans10_kernel(const float* __restrict__ Wq,
                                                       const float* __restrict__ Wk,
                                                       const float* __restrict__ Wv,
                                                       const float* __restrict__ W1,
                                                       const float* __restrict__ W2,
                                                       ushort_t* __restrict__ WqkvT,
                                                       ushort_t* __restrict__ W1T,
                                                       ushort_t* __restrict__ W2T) {
    __shared__ float ts[32][33];
    int tx = threadIdx.x & 31, ty = threadIdx.x >> 5;
    int bx = blockIdx.x * 32, by = blockIdx.y * 32;
    int z = blockIdx.z;
    const float* Wm;
    ushort_t* Wtm;
    if (z < 6) {
        int i = z / 3, j = z - 3 * i;
        const float* src = (j == 0) ? Wq : (j == 1) ? Wk : Wv;
        Wm = src + (size_t)i * DD * DD;
        Wtm = WqkvT + (size_t)z * DD * DD;
    } else if (z < 8) {
        Wm = W1 + (size_t)(z - 6) * DD * DD;
        Wtm = W1T + (size_t)(z - 6) * DD * DD;
    } else {
        Wm = W2 + (size_t)(z - 8) * DD * DD;
        Wtm = W2T + (size_t)(z - 8) * DD * DD;
    }
    #pragma unroll
    for (int i = 0; i < 4; i++) {
        int r = ty + i * 8;
        ts[r][tx] = Wm[(size_t)(by + r) * DD + bx + tx];
    }
    __syncthreads();
    #pragma unroll
    for (int i = 0; i < 4; i++) {
        int r = ty + i * 8;
        Wtm[(size_t)(bx + r) * DD + by + tx] = f2b(ts[tx][r]);
    }
}

// ---------------- layernorm: 128 threads/row, float4 loads (16B/lane) ----------
__global__ __launch_bounds__(128) void ln_kernel(const float* __restrict__ x,
                                                 const float* __restrict__ addx,
                                                 float* __restrict__ outf,
                                                 ushort_t* __restrict__ outb,
                                                 const float* __restrict__ g,
                                                 const float* __restrict__ bt,
                                                 const float* __restrict__ keepf) {
    int row = blockIdx.x;
    int t = threadIdx.x;          // 0..127, each owns 4 consecutive cols
    size_t base = (size_t)row * DD;
    f32x4 v = *(const f32x4*)(x + base + t * 4);
    if (addx) {
        f32x4 a = *(const f32x4*)(addx + base + t * 4);
        v = v + a;
    }
    float s = v[0] + v[1] + v[2] + v[3];
    float sq = v[0] * v[0] + v[1] * v[1] + v[2] * v[2] + v[3] * v[3];
    #pragma unroll
    for (int off = 32; off; off >>= 1) {
        s += __shfl_xor(s, off);
        sq += __shfl_xor(sq, off);
    }
    __shared__ float rs[2], rq[2];
    int wid = t >> 6, lane = t & 63;
    if (lane == 0) { rs[wid] = s; rq[wid] = sq; }
    __syncthreads();
    s = rs[0] + rs[1];
    sq = rq[0] + rq[1];
    float mean = s * (1.f / DD);
    float var = sq * (1.f / DD) - mean * mean;
    float rstd = rsqrtf(fmaxf(var, 0.f) + 1e-8f);
    float kf = keepf ? keepf[row] : 1.f;
    f32x4 gv = *(const f32x4*)(g + t * 4);
    f32x4 bv = *(const f32x4*)(bt + t * 4);
    f32x4 o;
    #pragma unroll
    for (int j = 0; j < 4; j++)
        o[j] = ((v[j] - mean) * rstd * gv[j] + bv[j]) * kf;
    if (outf) *(f32x4*)(outf + base + t * 4) = o;
    if (outb) {
        short4v ob;
        #pragma unroll
        for (int j = 0; j < 4; j++) ob[j] = (short)f2b(o[j]);
        *(short4v*)(outb + base + t * 4) = ob;
    }
}

// ---------------- bf16 MFMA GEMM, BK=64 via two 128x32 sub-tiles ----------------
// mode 1: Cb = bf16(relu(acc+bias)) ; mode 2: Cf = (Cf+acc+bias)*keepf
__global__ __launch_bounds__(256) void gemm_mfma(const ushort_t* __restrict__ A,
                                                 const ushort_t* __restrict__ Bt,
                                                 const float* __restrict__ bias,
                                                 float* __restrict__ Cf,
                                                 ushort_t* __restrict__ Cb,
                                                 const float* __restrict__ keepf,
                                                 int mode, int M, int N, int K) {
    __shared__ ushort_t sA[2][128 * 32];
    __shared__ ushort_t sB[2][128 * 32];
    int t = threadIdx.x;
    int w = t >> 6, lane = t & 63;
    int wm = w & 1, wn = w >> 1;
    int m0 = blockIdx.x * 128, n0 = blockIdx.y * 128;
    int lr = lane & 15, lq = lane >> 4;

    f32x4 acc[4][4] = {};

    for (int k0 = 0; k0 < K; k0 += 64) {
        #pragma unroll
        for (int hh = 0; hh < 2; hh++) {
            #pragma unroll
            for (int r = 0; r < 2; r++) {
                int e = (r * 256 + t) * 8;
                int row = e >> 5, col = e & 31;
                gload16(A + (size_t)(m0 + row) * K + k0 + hh * 32 + col,
                        sA[hh] + (r * 256 + w * 64) * 8);
                gload16(Bt + (size_t)(n0 + row) * K + k0 + hh * 32 + col,
                        sB[hh] + (r * 256 + w * 64) * 8);
            }
        }
        __syncthreads();

        #pragma unroll
        for (int hh = 0; hh < 2; hh++) {
            short8 af[4], bf[4];
            #pragma unroll
            for (int mt = 0; mt < 4; mt++)
                af[mt] = *(const short8*)(sA[hh] + (wm * 64 + mt * 16 + lr) * 32 + lq * 8);
            #pragma unroll
            for (int nt = 0; nt < 4; nt++)
                bf[nt] = *(const short8*)(sB[hh] + (wn * 64 + nt * 16 + lr) * 32 + lq * 8);
            #pragma unroll
            for (int mt = 0; mt < 4; mt++)
                #pragma unroll
                for (int nt = 0; nt < 4; nt++)
                    acc[mt][nt] = __builtin_amdgcn_mfma_f32_16x16x32_bf16(af[mt], bf[nt], acc[mt][nt], 0, 0, 0);
        }
        __syncthreads();
    }

    #pragma unroll
    for (int nt = 0; nt < 4; nt++) {
        int col = n0 + wn * 64 + nt * 16 + lr;
        float bv = bias[col];
        #pragma unroll
        for (int mt = 0; mt < 4; mt++) {
            int rowb = m0 + wm * 64 + mt * 16 + lq * 4;
            #pragma unroll
            for (int r = 0; r < 4; r++) {
                int row = rowb + r;
                float o = acc[mt][nt][r] + bv;
                size_t idx = (size_t)row * N + col;
                if (mode == 1) {
                    Cb[idx] = f2b(fmaxf(o, 0.f));
                } else {
                    float kf = keepf[row];
                    Cf[idx] = (Cf[idx] + o) * kf;
                }
            }
        }
    }
}

// ---------------- fused Q/K/V projection: grid (200, 4, 3), BK=64 sub-tiles ----
// z==2 (V) writes TRANSPOSED into vt[(b*8+h)*64 + d][key] with key pitch LLP=232,
// exactly the layout attention's LDS wants -> attention stages it with a pure
// global_load_lds memcpy (no VALU transpose). 4 acc rows of one fragment are
// 4 consecutive keys of one d (200%4==0, rowb%4==0 -> never straddles b) => 8B store.
__global__ __launch_bounds__(256) void gemm_qkv(const ushort_t* __restrict__ Aq,
                                                const ushort_t* __restrict__ Akv,
                                                const ushort_t* __restrict__ Bqkv,
                                                const float* __restrict__ bq,
                                                const float* __restrict__ bk,
                                                const float* __restrict__ bv,
                                                ushort_t* __restrict__ qkv,
                                                ushort_t* __restrict__ vt) {
    __shared__ ushort_t sA[2][128 * 32];
    __shared__ ushort_t sB[2][128 * 32];
    int z = blockIdx.z;
    const ushort_t* A = (z == 0) ? Aq : Akv;
    const ushort_t* Bt = Bqkv + (size_t)z * DD * DD;
    const float* bias = (z == 0) ? bq : (z == 1) ? bk : bv;
    ushort_t* C = qkv + (size_t)z * BL * DD;   // used only for z<2

    int t = threadIdx.x;
    int w = t >> 6, lane = t & 63;
    int wm = w & 1, wn = w >> 1;
    int m0 = blockIdx.x * 128, n0 = blockIdx.y * 128;
    int lr = lane & 15, lq = lane >> 4;

    f32x4 acc[4][4] = {};

    for (int k0 = 0; k0 < DD; k0 += 64) {
        #pragma unroll
        for (int hh = 0; hh < 2; hh++) {
            #pragma unroll
            for (int r = 0; r < 2; r++) {
                int e = (r * 256 + t) * 8;
                int row = e >> 5, col = e & 31;
                gload16(A + (size_t)(m0 + row) * DD + k0 + hh * 32 + col,
                        sA[hh] + (r * 256 + w * 64) * 8);
                gload16(Bt + (size_t)(n0 + row) * DD + k0 + hh * 32 + col,
                        sB[hh] + (r * 256 + w * 64) * 8);
            }
        }
        __syncthreads();

        #pragma unroll
        for (int hh = 0; hh < 2; hh++) {
            short8 af[4], bf[4];
            #pragma unroll
            for (int mt = 0; mt < 4; mt++)
                af[mt] = *(const short8*)(sA[hh] + (wm * 64 + mt * 16 + lr) * 32 + lq * 8);
            #pragma unroll
            for (int nt = 0; nt < 4; nt++)
                bf[nt] = *(const short8*)(sB[hh] + (wn * 64 + nt * 16 + lr) * 32 + lq * 8);
            #pragma unroll
            for (int mt = 0; mt < 4; mt++)
                #pragma unroll
                for (int nt = 0; nt < 4; nt++)
                    acc[mt][nt] = __builtin_amdgcn_mfma_f32_16x16x32_bf16(af[mt], bf[nt], acc[mt][nt], 0, 0, 0);
        }
        __syncthreads();
    }

    #pragma unroll
    for (int nt = 0; nt < 4; nt++) {
        int col = n0 + wn * 64 + nt * 16 + lr;
        float bv2 = bias[col];
        if (z == 2) {
            int h2 = col >> 6, d2 = col & 63;
            #pragma unroll
            for (int mt = 0; mt < 4; mt++) {
                int rowb = m0 + wm * 64 + mt * 16 + lq * 4;
                int bi = rowb / LL;
                int key0 = rowb - bi * LL;
                short4v pk;
                #pragma unroll
                for (int r = 0; r < 4; r++)
                    pk[r] = (short)f2b(acc[mt][nt][r] + bv2);
                *(short4v*)(vt + ((size_t)((bi * HH + h2) * DK + d2)) * LLP + key0) = pk;
            }
        } else {
            #pragma unroll
            for (int mt = 0; mt < 4; mt++) {
                int rowb = m0 + wm * 64 + mt * 16 + lq * 4;
                #pragma unroll
                for (int r = 0; r < 4; r++) {
                    int row = rowb + r;
                    C[(size_t)row * DD + col] = f2b(acc[mt][nt][r] + bv2);
                }
            }
        }
    }
}

// ---------------- attention v7: LDS V^T staged via pure memcpy ------------------
// Round-1 lesson: V^T direct-from-global re-read per qtile blew HBM traffic to
// 431 MB/dispatch (82 MB working set >> 32 MB L2). Here V^T is read from HBM ONCE
// per block into LDS — but since gemm_qkv already wrote it transposed at pitch 232,
// staging is a contiguous global_load_lds memcpy (attn5's VALU transpose is gone).
// Softmax stays fused (1 pass, 2 barriers/qtile, from round 1 — verified).
#define ATTN_LDS_BYTES 61440
__global__ __launch_bounds__(256, 2) void attn7_kernel(const ushort_t* __restrict__ q,
                                                       const ushort_t* __restrict__ k,
                                                       const ushort_t* __restrict__ vt,
                                                       const float* __restrict__ kmf,
                                                       float* __restrict__ xout) {
    extern __shared__ ushort_t su[];
    ushort_t* sP = su;                    // [64][232] bf16
    ushort_t* sVt = su + 14848;           // [64][232] bf16 (29,696 B)
    float* redm = (float*)(su + 29696);   // [256] per-wave row max
    float* reds = redm + 256;             // [256] per-wave row sum

    int t = threadIdx.x;
    int b = blockIdx.x >> 3, h = blockIdx.x & 7;
    int w = t >> 6, lane = t & 63;
    int lr = lane & 15, lq = lane >> 4;

    const ushort_t* kg = k + (size_t)b * LL * DD + h * DK;
    const ushort_t* qg = q + (size_t)b * LL * DD + h * DK;
    const ushort_t* vtg = vt + (size_t)(b * HH + h) * DK * LLP;
    float* og = xout + (size_t)b * LL * DD + h * DK;

    // stage V^T: contiguous 64*232 ushorts = 1856 x 16B chunks. LDS dest is
    // wave-uniform base + lane*16 (global_load_lds constraint satisfied).
    #pragma unroll
    for (int it = 0; it < 8; it++) {
        int idx = it * 256 + t;
        if (idx < 1856)     // wave-uniform branch (tail it=7: wave 0 only)
            gload16(vtg + (size_t)idx * 8, sVt + (size_t)idx * 8);
    }
    // first sVt read is after >=2 __syncthreads() (each drains vmcnt) — no barrier here

    // K fragments + key masks hoisted across qtiles (wave w owns keys w*64..+63)
    short8 bfK[2][4];
    float km[4];
    #pragma unroll
    for (int nt = 0; nt < 4; nt++) {
        int j = w * 64 + nt * 16 + lr;
        int jc = (j < LL) ? j : (LL - 1);
        #pragma unroll
        for (int ks = 0; ks < 2; ks++)
            bfK[ks][nt] = *(const short8*)(kg + (size_t)jc * DD + ks * 32 + lq * 8);
        km[nt] = (j < LL) ? kmf[b * LL + j] : 0.f;
    }

    for (int qt = 0; qt < 4; qt++) {
        int q0 = qt * 64;

        // S = Q @ K^T ; Q frags loaded per k-slice to bound register lifetime
        f32x4 accS[4][4] = {};
        #pragma unroll
        for (int ks = 0; ks < 2; ks++) {
            short8 af[4];
            #pragma unroll
            for (int mt = 0; mt < 4; mt++) {
                int grow = q0 + mt * 16 + lr;
                if (grow > LL - 1) grow = LL - 1;
                af[mt] = *(const short8*)(qg + (size_t)grow * DD + ks * 32 + lq * 8);
            }
            #pragma unroll
            for (int nt = 0; nt < 4; nt++)
                #pragma unroll
                for (int mt = 0; mt < 4; mt++)
                    accS[mt][nt] = __builtin_amdgcn_mfma_f32_16x16x32_bf16(af[mt], bfK[ks][nt], accS[mt][nt], 0, 0, 0);
        }

        // fused: mask + scale + wave-local max + exp + wave-local sum (1 pass)
        float rmax[4][4];
        #pragma unroll
        for (int mt = 0; mt < 4; mt++) {
            #pragma unroll
            for (int r = 0; r < 4; r++) {
                int qrow = q0 + mt * 16 + lq * 4 + r;
                float m = -1e9f;
                #pragma unroll
                for (int nt = 0; nt < 4; nt++) {
                    int j = w * 64 + nt * 16 + lr;
                    bool ok = (j <= qrow) && (km[nt] != 0.f);
                    float s = ok ? accS[mt][nt][r] * 0.125f : -1e9f;
                    accS[mt][nt][r] = s;
                    m = fmaxf(m, s);
                }
                #pragma unroll
                for (int off = 1; off < 16; off <<= 1)
                    m = fmaxf(m, __shfl_xor(m, off));
                rmax[mt][r] = m;
                float ps = 0.f;
                #pragma unroll
                for (int nt = 0; nt < 4; nt++) {
                    float e = __expf(accS[mt][nt][r] - m);
                    accS[mt][nt][r] = e;
                    ps += e;
                }
                #pragma unroll
                for (int off = 1; off < 16; off <<= 1)
                    ps += __shfl_xor(ps, off);
                if (lr == 0) {
                    int row = mt * 16 + lq * 4 + r;
                    redm[w * 64 + row] = m;
                    reds[w * 64 + row] = ps;
                }
            }
        }
        __syncthreads();

        // combine waves: M = max_w m_w, tot = sum_w s_w*exp(m_w-M); normalize -> bf16 P
        #pragma unroll
        for (int mt = 0; mt < 4; mt++) {
            #pragma unroll
            for (int r = 0; r < 4; r++) {
                int row = mt * 16 + lq * 4 + r;
                float mw0 = redm[row], mw1 = redm[64 + row];
                float mw2 = redm[128 + row], mw3 = redm[192 + row];
                float gm = fmaxf(fmaxf(mw0, mw1), fmaxf(mw2, mw3));
                float tot = reds[row] * __expf(mw0 - gm)
                          + reds[64 + row] * __expf(mw1 - gm)
                          + reds[128 + row] * __expf(mw2 - gm)
                          + reds[192 + row] * __expf(mw3 - gm);
                // all-masked row -> gm=-1e9 -> inv=0 -> exact zeros (double masking)
                float inv = (gm < -5e8f) ? 0.f : __expf(rmax[mt][r] - gm) / tot;
                #pragma unroll
                for (int nt = 0; nt < 4; nt++) {
                    int col = w * 64 + nt * 16 + lr;
                    if (col < 224)
                        sP[row * 232 + col] = f2b(accS[mt][nt][r] * inv);
                }
            }
        }
        __syncthreads();

        // O = P @ V ; wave w owns d-tile w*16..+15 ; keys 0..223 (tail zeroed)
        f32x4 accO[4] = {};
        #pragma unroll
        for (int ks2 = 0; ks2 < 7; ks2++) {
            short8 bfv = *(const short8*)(sVt + (w * 16 + lr) * 232 + ks2 * 32 + lq * 8);
            #pragma unroll
            for (int mt = 0; mt < 4; mt++) {
                short8 afp = *(const short8*)(sP + (mt * 16 + lr) * 232 + ks2 * 32 + lq * 8);
                accO[mt] = __builtin_amdgcn_mfma_f32_16x16x32_bf16(afp, bfv, accO[mt], 0, 0, 0);
            }
        }
        #pragma unroll
        for (int mt = 0; mt < 4; mt++) {
            #pragma unroll
            for (int r = 0; r < 4; r++) {
                int row = q0 + mt * 16 + lq * 4 + r;
                if (row < LL)
                    og[(size_t)row * DD + w * 16 + lr] = accO[mt][r];
            }
        }
        // no end-of-qtile barrier: next qtile's sP/redm writes happen only after
        // its own first barrier, which already orders them vs. these reads
    }
}

extern "C" void kernel_launch(void* const* d_in, const int* in_sizes, int n_in,
                              void* d_out, int out_size, void* d_ws, size_t ws_size,
                              hipStream_t stream) {
    const int* log_seqs = (const int*)d_in[0];
    const float* seqs_embs = (const float*)d_in[1];
    const int* entire = (const int*)d_in[2];
    const float* Wq = (const float*)d_in[3];
    const float* bq = (const float*)d_in[4];
    const float* Wk = (const float*)d_in[5];
    const float* bk = (const float*)d_in[6];
    const float* Wv = (const float*)d_in[7];
    const float* bv = (const float*)d_in[8];
    const float* lag = (const float*)d_in[9];
    const float* lab = (const float*)d_in[10];
    const float* lfg = (const float*)d_in[11];
    const float* lfb = (const float*)d_in[12];
    const float* W1 = (const float*)d_in[13];
    const float* b1 = (const float*)d_in[14];
    const float* W2 = (const float*)d_in[15];
    const float* b2 = (const float*)d_in[16];
    const float* llg = (const float*)d_in[17];
    const float* llb = (const float*)d_in[18];
    float* out = (float*)d_out;
    float* ws = (float*)d_ws;

    hipFuncSetAttribute((const void*)attn7_kernel,
                        hipFuncAttributeMaxDynamicSharedMemorySize,
                        ATTN_LDS_BYTES);

    // workspace ~246 MB (262.45 MB proven safe)
    const size_t n = (size_t)BL * DD;
    float* tgt = ws;
    float* aout = ws + n;
    ushort_t* srcb = (ushort_t*)(ws + 2 * n);
    ushort_t* qb = srcb + n;
    ushort_t* kb = qb + n;
    ushort_t* lnb = kb + n;          // dedicated: read by gemm_qkv z=0 while z writes qb/kb/vt
    ushort_t* WqkvT = lnb + n;
    ushort_t* W1T = WqkvT + (size_t)NBLK * 3 * DD * DD;
    ushort_t* W2T = W1T + (size_t)NBLK * DD * DD;
    float* keepf = (float*)(W2T + (size_t)NBLK * DD * DD);
    float* kmf = keepf + BL;
    ushort_t* vt = (ushort_t*)(kmf + BL);   // [BB*HH*DK][LLP] bf16 V^T (30.4 MB)
    ushort_t* hb = qb;               // FFN1 out: qb dead after attention

    mask_kernel<<<(BL + 255) / 256, 256, 0, stream>>>(log_seqs, entire, keepf, kmf);
    prep_kernel<<<BL, 256, 0, stream>>>(log_seqs, seqs_embs, tgt, srcb);
    dim3 tw(16, 16, 10);
    wtrans10_kernel<<<tw, 256, 0, stream>>>(Wq, Wk, Wv, W1, W2, WqkvT, W1T, W2T);
    vtail_kernel<<<(BB * HH * DK * 8 + 255) / 256, 256, 0, stream>>>(vt);

    dim3 gg(BL / 128, DD / 128);
    dim3 gq(BL / 128, DD / 128, 3);
    for (int i = 0; i < NBLK; i++) {
        size_t wo = (size_t)i * DD * DD;
        // lnb = bf16(LN(tgt, ln_attn))
        ln_kernel<<<BL, 128, 0, stream>>>(tgt, nullptr, nullptr, lnb,
                                          lag + i * DD, lab + i * DD, nullptr);
        // fused q,k,v projections -> qb,kb (bf16) + vt (bf16, transposed, pitch 232)
        gemm_qkv<<<gq, 256, 0, stream>>>(lnb, srcb, WqkvT + (size_t)i * 3 * DD * DD,
                                         bq + i * DD, bk + i * DD, bv + i * DD, qb, vt);
        // attention (MFMA) -> aout fp32
        attn7_kernel<<<BB * HH, 256, ATTN_LDS_BYTES, stream>>>(qb, kb, vt, kmf, aout);
        // tgt = LN(aout (+tgt)), bf16 copy to lnb
        ln_kernel<<<BL, 128, 0, stream>>>(aout, (i == 0) ? nullptr : tgt, tgt, lnb,
                                          lfg + i * DD, lfb + i * DD, nullptr);
        // hb = bf16(relu(lnb @ W1 + b1))
        gemm_mfma<<<gg, 256, 0, stream>>>(lnb, W1T + wo, b1 + i * DD, nullptr, hb,
                                          nullptr, 1, BL, DD, DD);
        // tgt = (tgt + hb @ W2 + b2) * keep
        gemm_mfma<<<gg, 256, 0, stream>>>(hb, W2T + wo, b2 + i * DD, tgt, nullptr,
                                          keepf, 2, BL, DD, DD);
    }
    ln_kernel<<<BL, 128, 0, stream>>>(tgt, nullptr, out, nullptr, llg, llb, keepf);
}

// Round 3
// 736.511 us; speedup vs baseline: 1.4706x; 1.0665x over previous
//
#include <hip/hip_runtime.h>
#include <hip/hip_bf16.h>

#define BB 128
#define LL 200
#define DD 512
#define HH 8
#define DK 64
#define NBLK 2
#define BL (BB*LL)
#define LLP 232   // V^T key pitch (ushorts): 224 used + 8 pad; 232-pitch gives the
                  // proven 2-way-max LDS/frag bank pattern and 16B alignment

typedef unsigned short ushort_t;
typedef unsigned int uint_t;
typedef __attribute__((ext_vector_type(8))) short short8;
typedef __attribute__((ext_vector_type(4))) short short4v;
typedef __attribute__((ext_vector_type(4))) float f32x4;

__device__ inline ushort_t f2b(float x) {
    unsigned u = __float_as_uint(x);
    unsigned r = (u + 0x7FFF + ((u >> 16) & 1)) >> 16;
    return (ushort_t)r;
}

__device__ inline void gload16(const void* g, void* l) {
    __builtin_amdgcn_global_load_lds((const __attribute__((address_space(1))) void*)g,
                                     (__attribute__((address_space(3))) void*)l,
                                     16, 0, 0);
}

// ---------------- masks (keepf, kmf) ----------------
__global__ __launch_bounds__(256) void mask_kernel(const int* __restrict__ logs,
                                                   const int* __restrict__ entire,
                                                   float* __restrict__ keepf,
                                                   float* __restrict__ kmf) {
    int i = blockIdx.x * 256 + threadIdx.x;
    if (i < BL) {
        keepf[i] = (logs[i] == 0) ? 0.f : 1.f;
        kmf[i] = (logs[i] == 0 && entire[i] != 0) ? 1.f : 0.f;
    }
}

// zero the key-tail (keys 200..231) of V^T once; gemm_qkv only writes keys<200.
// REQUIRED: P is exactly 0 for masked keys, but 0*NaN(garbage V)=NaN in MFMA.
__global__ __launch_bounds__(256) void vtail_kernel(ushort_t* __restrict__ vt) {
    int i = blockIdx.x * 256 + threadIdx.x;
    if (i < BB * HH * DK * 8) {
        int row = i >> 3, c = i & 7;
        *(unsigned long long*)(vt + (size_t)row * LLP + LL + c * 4) = 0ULL;
    }
}

// fused: tgt = emb*keep (fp32) ; srcb = bf16(emb*tl) — one emb read
__global__ __launch_bounds__(256) void prep_kernel(const int* __restrict__ logs,
                                                   const float* __restrict__ emb,
                                                   float* __restrict__ tgt,
                                                   ushort_t* __restrict__ srcb) {
    int row = blockIdx.x;
    int t = threadIdx.x;
    bool src = (logs[row] == 0);
    float kf = src ? 0.f : 1.f, sf = src ? 1.f : 0.f;
    size_t base = (size_t)row * DD;
    float e0 = emb[base + t], e1 = emb[base + t + 256];
    tgt[base + t] = e0 * kf;
    tgt[base + t + 256] = e1 * kf;
    srcb[base + t] = f2b(e0 * sf);
    srcb[base + t + 256] = f2b(e1 * sf);
}

// fused weight transpose + bf16 for all 10 matrices: grid (16,16,10)
__global__ __launch_bounds__(256) void wtrans10_kernel(const float* __restrict__ Wq,
                                                       const float* __restrict__ Wk,
                                                       const float* __restrict__ Wv,
                                                       const float* __restrict__ W1,
                                                       const float* __restrict__ W2,
                                                       ushort_t* __restrict__ WqkvT,
                                                       ushort_t* __restrict__ W1T,
                                                       ushort_t* __restrict__ W2T) {
    __shared__ float ts[32][33];
    int tx = threadIdx.x & 31, ty = threadIdx.x >> 5;
    int bx = blockIdx.x * 32, by = blockIdx.y * 32;
    int z = blockIdx.z;
    const float* Wm;
    ushort_t* Wtm;
    if (z < 6) {
        int i = z / 3, j = z - 3 * i;
        const float* src = (j == 0) ? Wq : (j == 1) ? Wk : Wv;
        Wm = src + (size_t)i * DD * DD;
        Wtm = WqkvT + (size_t)z * DD * DD;
    } else if (z < 8) {
        Wm = W1 + (size_t)(z - 6) * DD * DD;
        Wtm = W1T + (size_t)(z - 6) * DD * DD;
    } else {
        Wm = W2 + (size_t)(z - 8) * DD * DD;
        Wtm = W2T + (size_t)(z - 8) * DD * DD;
    }
    #pragma unroll
    for (int i = 0; i < 4; i++) {
        int r = ty + i * 8;
        ts[r][tx] = Wm[(size_t)(by + r) * DD + bx + tx];
    }
    __syncthreads();
    #pragma unroll
    for (int i = 0; i < 4; i++) {
        int r = ty + i * 8;
        Wtm[(size_t)(bx + r) * DD + by + tx] = f2b(ts[tx][r]);
    }
}

// ---------------- layernorm: 128 threads/row, float4 loads (16B/lane) ----------
__global__ __launch_bounds__(128) void ln_kernel(const float* __restrict__ x,
                                                 const float* __restrict__ addx,
                                                 float* __restrict__ outf,
                                                 ushort_t* __restrict__ outb,
                                                 const float* __restrict__ g,
                                                 const float* __restrict__ bt,
                                                 const float* __restrict__ keepf) {
    int row = blockIdx.x;
    int t = threadIdx.x;          // 0..127, each owns 4 consecutive cols
    size_t base = (size_t)row * DD;
    f32x4 v = *(const f32x4*)(x + base + t * 4);
    if (addx) {
        f32x4 a = *(const f32x4*)(addx + base + t * 4);
        v = v + a;
    }
    float s = v[0] + v[1] + v[2] + v[3];
    float sq = v[0] * v[0] + v[1] * v[1] + v[2] * v[2] + v[3] * v[3];
    #pragma unroll
    for (int off = 32; off; off >>= 1) {
        s += __shfl_xor(s, off);
        sq += __shfl_xor(sq, off);
    }
    __shared__ float rs[2], rq[2];
    int wid = t >> 6, lane = t & 63;
    if (lane == 0) { rs[wid] = s; rq[wid] = sq; }
    __syncthreads();
    s = rs[0] + rs[1];
    sq = rq[0] + rq[1];
    float mean = s * (1.f / DD);
    float var = sq * (1.f / DD) - mean * mean;
    float rstd = rsqrtf(fmaxf(var, 0.f) + 1e-8f);
    float kf = keepf ? keepf[row] : 1.f;
    f32x4 gv = *(const f32x4*)(g + t * 4);
    f32x4 bv = *(const f32x4*)(bt + t * 4);
    f32x4 o;
    #pragma unroll
    for (int j = 0; j < 4; j++)
        o[j] = ((v[j] - mean) * rstd * gv[j] + bv[j]) * kf;
    if (outf) *(f32x4*)(outf + base + t * 4) = o;
    if (outb) {
        short4v ob;
        #pragma unroll
        for (int j = 0; j < 4; j++) ob[j] = (short)f2b(o[j]);
        *(short4v*)(outb + base + t * 4) = ob;
    }
}

// ---------------- bf16 MFMA GEMM, BK=64 via two 128x32 sub-tiles ----------------
// mode 1: Cb = bf16(relu(acc+bias)) ; mode 2: Cf = (Cf+acc+bias)*keepf
__global__ __launch_bounds__(256) void gemm_mfma(const ushort_t* __restrict__ A,
                                                 const ushort_t* __restrict__ Bt,
                                                 const float* __restrict__ bias,
                                                 float* __restrict__ Cf,
                                                 ushort_t* __restrict__ Cb,
                                                 const float* __restrict__ keepf,
                                                 int mode, int M, int N, int K) {
    __shared__ ushort_t sA[2][128 * 32];
    __shared__ ushort_t sB[2][128 * 32];
    int t = threadIdx.x;
    int w = t >> 6, lane = t & 63;
    int wm = w & 1, wn = w >> 1;
    int m0 = blockIdx.x * 128, n0 = blockIdx.y * 128;
    int lr = lane & 15, lq = lane >> 4;

    f32x4 acc[4][4] = {};

    for (int k0 = 0; k0 < K; k0 += 64) {
        #pragma unroll
        for (int hh = 0; hh < 2; hh++) {
            #pragma unroll
            for (int r = 0; r < 2; r++) {
                int e = (r * 256 + t) * 8;
                int row = e >> 5, col = e & 31;
                gload16(A + (size_t)(m0 + row) * K + k0 + hh * 32 + col,
                        sA[hh] + (r * 256 + w * 64) * 8);
                gload16(Bt + (size_t)(n0 + row) * K + k0 + hh * 32 + col,
                        sB[hh] + (r * 256 + w * 64) * 8);
            }
        }
        __syncthreads();

        #pragma unroll
        for (int hh = 0; hh < 2; hh++) {
            short8 af[4], bf[4];
            #pragma unroll
            for (int mt = 0; mt < 4; mt++)
                af[mt] = *(const short8*)(sA[hh] + (wm * 64 + mt * 16 + lr) * 32 + lq * 8);
            #pragma unroll
            for (int nt = 0; nt < 4; nt++)
                bf[nt] = *(const short8*)(sB[hh] + (wn * 64 + nt * 16 + lr) * 32 + lq * 8);
            #pragma unroll
            for (int mt = 0; mt < 4; mt++)
                #pragma unroll
                for (int nt = 0; nt < 4; nt++)
                    acc[mt][nt] = __builtin_amdgcn_mfma_f32_16x16x32_bf16(af[mt], bf[nt], acc[mt][nt], 0, 0, 0);
        }
        __syncthreads();
    }

    #pragma unroll
    for (int nt = 0; nt < 4; nt++) {
        int col = n0 + wn * 64 + nt * 16 + lr;
        float bv = bias[col];
        #pragma unroll
        for (int mt = 0; mt < 4; mt++) {
            int rowb = m0 + wm * 64 + mt * 16 + lq * 4;
            #pragma unroll
            for (int r = 0; r < 4; r++) {
                int row = rowb + r;
                float o = acc[mt][nt][r] + bv;
                size_t idx = (size_t)row * N + col;
                if (mode == 1) {
                    Cb[idx] = f2b(fmaxf(o, 0.f));
                } else {
                    float kf = keepf[row];
                    Cf[idx] = (Cf[idx] + o) * kf;
                }
            }
        }
    }
}

// ---------------- fused Q/K/V projection: grid (200, 4, 3), BK=64 sub-tiles ----
// z==2 (V) writes TRANSPOSED into vt[(b*8+h)*64 + d][key] with key pitch LLP=232.
// 4 acc rows of one fragment are 4 consecutive keys of one d (200%4==0,
// rowb%4==0 -> never straddles b) => 8B store.
__global__ __launch_bounds__(256) void gemm_qkv(const ushort_t* __restrict__ Aq,
                                                const ushort_t* __restrict__ Akv,
                                                const ushort_t* __restrict__ Bqkv,
                                                const float* __restrict__ bq,
                                                const float* __restrict__ bk,
                                                const float* __restrict__ bv,
                                                ushort_t* __restrict__ qkv,
                                                ushort_t* __restrict__ vt) {
    __shared__ ushort_t sA[2][128 * 32];
    __shared__ ushort_t sB[2][128 * 32];
    int z = blockIdx.z;
    const ushort_t* A = (z == 0) ? Aq : Akv;
    const ushort_t* Bt = Bqkv + (size_t)z * DD * DD;
    const float* bias = (z == 0) ? bq : (z == 1) ? bk : bv;
    ushort_t* C = qkv + (size_t)z * BL * DD;   // used only for z<2

    int t = threadIdx.x;
    int w = t >> 6, lane = t & 63;
    int wm = w & 1, wn = w >> 1;
    int m0 = blockIdx.x * 128, n0 = blockIdx.y * 128;
    int lr = lane & 15, lq = lane >> 4;

    f32x4 acc[4][4] = {};

    for (int k0 = 0; k0 < DD; k0 += 64) {
        #pragma unroll
        for (int hh = 0; hh < 2; hh++) {
            #pragma unroll
            for (int r = 0; r < 2; r++) {
                int e = (r * 256 + t) * 8;
                int row = e >> 5, col = e & 31;
                gload16(A + (size_t)(m0 + row) * DD + k0 + hh * 32 + col,
                        sA[hh] + (r * 256 + w * 64) * 8);
                gload16(Bt + (size_t)(n0 + row) * DD + k0 + hh * 32 + col,
                        sB[hh] + (r * 256 + w * 64) * 8);
            }
        }
        __syncthreads();

        #pragma unroll
        for (int hh = 0; hh < 2; hh++) {
            short8 af[4], bf[4];
            #pragma unroll
            for (int mt = 0; mt < 4; mt++)
                af[mt] = *(const short8*)(sA[hh] + (wm * 64 + mt * 16 + lr) * 32 + lq * 8);
            #pragma unroll
            for (int nt = 0; nt < 4; nt++)
                bf[nt] = *(const short8*)(sB[hh] + (wn * 64 + nt * 16 + lr) * 32 + lq * 8);
            #pragma unroll
            for (int mt = 0; mt < 4; mt++)
                #pragma unroll
                for (int nt = 0; nt < 4; nt++)
                    acc[mt][nt] = __builtin_amdgcn_mfma_f32_16x16x32_bf16(af[mt], bf[nt], acc[mt][nt], 0, 0, 0);
        }
        __syncthreads();
    }

    #pragma unroll
    for (int nt = 0; nt < 4; nt++) {
        int col = n0 + wn * 64 + nt * 16 + lr;
        float bv2 = bias[col];
        if (z == 2) {
            int h2 = col >> 6, d2 = col & 63;
            #pragma unroll
            for (int mt = 0; mt < 4; mt++) {
                int rowb = m0 + wm * 64 + mt * 16 + lq * 4;
                int bi = rowb / LL;
                int key0 = rowb - bi * LL;
                short4v pk;
                #pragma unroll
                for (int r = 0; r < 4; r++)
                    pk[r] = (short)f2b(acc[mt][nt][r] + bv2);
                *(short4v*)(vt + ((size_t)((bi * HH + h2) * DK + d2)) * LLP + key0) = pk;
            }
        } else {
            #pragma unroll
            for (int mt = 0; mt < 4; mt++) {
                int rowb = m0 + wm * 64 + mt * 16 + lq * 4;
                #pragma unroll
                for (int r = 0; r < 4; r++) {
                    int row = rowb + r;
                    C[(size_t)row * DD + col] = f2b(acc[mt][nt][r] + bv2);
                }
            }
        }
    }
}

// ---------------- attention v8: K+V^T in registers, sP-only LDS, 4 blocks/CU ---
// Rounds 0-2 showed: latency-bound (Occ 21%, MfmaUtil 5%, HBM 10%), 2 blocks/CU
// = 2 sequential rounds. Fix: qtile=32 rows -> accS 32 VGPR; K frags (32 VGPR) +
// V^T frags (28 VGPR) hoisted once per block (single HBM read, round-1 lesson:
// never re-read V from global per qtile). LDS = sP[32][232]+red = 15,872 B.
// VGPR<=128 via __launch_bounds__(256,4) -> 16 waves/CU, 1024 blocks = ONE round.
// Causal skipping (exact): qtile qt needs keys < 32(qt+1); wave w (keys 64w..+63)
// does QK^T/softmax only if 2w <= qt; PV truncates at ks2 <= qt; qt<7 (rows>=224 dead).
__global__ __launch_bounds__(256, 4) void attn8_kernel(const ushort_t* __restrict__ q,
                                                       const ushort_t* __restrict__ k,
                                                       const ushort_t* __restrict__ vt,
                                                       const float* __restrict__ kmf,
                                                       float* __restrict__ xout) {
    __shared__ ushort_t sP[32 * 232];   // 14,848 B
    __shared__ float redm[128];         // [4 waves][32 rows]
    __shared__ float reds[128];

    int t = threadIdx.x;
    int b = blockIdx.x >> 3, h = blockIdx.x & 7;
    int w = t >> 6, lane = t & 63;
    int lr = lane & 15, lq = lane >> 4;

    const ushort_t* kg = k + (size_t)b * LL * DD + h * DK;
    const ushort_t* qg = q + (size_t)b * LL * DD + h * DK;
    const ushort_t* vtg = vt + (size_t)(b * HH + h) * DK * LLP;
    float* og = xout + (size_t)b * LL * DD + h * DK;

    // K fragments + key masks + V^T fragments: loaded ONCE per block (qtile-invariant)
    short8 bfK[2][4];
    float km[4];
    #pragma unroll
    for (int nt = 0; nt < 4; nt++) {
        int j = w * 64 + nt * 16 + lr;
        int jc = (j < LL) ? j : (LL - 1);
        #pragma unroll
        for (int ks = 0; ks < 2; ks++)
            bfK[ks][nt] = *(const short8*)(kg + (size_t)jc * DD + ks * 32 + lq * 8);
        km[nt] = (j < LL) ? kmf[b * LL + j] : 0.f;
    }
    short8 bfv[7];   // wave w owns output d-tile w*16..+15; keys ks2*32+lq*8..+7
    #pragma unroll
    for (int ks2 = 0; ks2 < 7; ks2++)
        bfv[ks2] = *(const short8*)(vtg + (size_t)(w * 16 + lr) * LLP + ks2 * 32 + lq * 8);

    for (int qt = 0; qt < 7; qt++) {
        int q0 = qt * 32;
        bool active = (2 * w <= qt);   // wave-uniform: any key 64w..64w+63 <= q0+31?

        float rmax[2][4];
        f32x4 accS[2][4] = {};
        if (active) {
            // S = Q @ K^T for this wave's 64 keys
            #pragma unroll
            for (int ks = 0; ks < 2; ks++) {
                short8 af[2];
                #pragma unroll
                for (int mt = 0; mt < 2; mt++) {
                    int grow = q0 + mt * 16 + lr;
                    if (grow > LL - 1) grow = LL - 1;
                    af[mt] = *(const short8*)(qg + (size_t)grow * DD + ks * 32 + lq * 8);
                }
                #pragma unroll
                for (int nt = 0; nt < 4; nt++)
                    #pragma unroll
                    for (int mt = 0; mt < 2; mt++)
                        accS[mt][nt] = __builtin_amdgcn_mfma_f32_16x16x32_bf16(af[mt], bfK[ks][nt], accS[mt][nt], 0, 0, 0);
            }
            // fused: mask + scale + wave-local max + exp + wave-local sum
            #pragma unroll
            for (int mt = 0; mt < 2; mt++) {
                #pragma unroll
                for (int r = 0; r < 4; r++) {
                    int qrow = q0 + mt * 16 + lq * 4 + r;
                    float m = -1e9f;
                    #pragma unroll
                    for (int nt = 0; nt < 4; nt++) {
                        int j = w * 64 + nt * 16 + lr;
                        bool ok = (j <= qrow) && (km[nt] != 0.f);
                        float s = ok ? accS[mt][nt][r] * 0.125f : -1e9f;
                        accS[mt][nt][r] = s;
                        m = fmaxf(m, s);
                    }
                    #pragma unroll
                    for (int off = 1; off < 16; off <<= 1)
                        m = fmaxf(m, __shfl_xor(m, off));
                    rmax[mt][r] = m;
                    float ps = 0.f;
                    #pragma unroll
                    for (int nt = 0; nt < 4; nt++) {
                        float e = __expf(accS[mt][nt][r] - m);
                        accS[mt][nt][r] = e;
                        ps += e;
                    }
                    #pragma unroll
                    for (int off = 1; off < 16; off <<= 1)
                        ps += __shfl_xor(ps, off);
                    if (lr == 0) {
                        int row = mt * 16 + lq * 4 + r;
                        redm[w * 32 + row] = m;
                        reds[w * 32 + row] = ps;
                    }
                }
            }
        } else {
            // fully-masked wave: contribute identity to the cross-wave reduction
            if (lr == 0) {
                #pragma unroll
                for (int mt = 0; mt < 2; mt++)
                    #pragma unroll
                    for (int r = 0; r < 4; r++) {
                        int row = mt * 16 + lq * 4 + r;
                        redm[w * 32 + row] = -1e9f;
                        reds[w * 32 + row] = 0.f;
                    }
            }
        }
        __syncthreads();

        // combine waves + normalize -> bf16 P (active waves only; inactive waves'
        // columns >= 32(qt+1) are never read by the truncated PV loop)
        if (active) {
            #pragma unroll
            for (int mt = 0; mt < 2; mt++) {
                #pragma unroll
                for (int r = 0; r < 4; r++) {
                    int row = mt * 16 + lq * 4 + r;
                    float mw0 = redm[row], mw1 = redm[32 + row];
                    float mw2 = redm[64 + row], mw3 = redm[96 + row];
                    float gm = fmaxf(fmaxf(mw0, mw1), fmaxf(mw2, mw3));
                    float tot = reds[row] * __expf(mw0 - gm)
                              + reds[32 + row] * __expf(mw1 - gm)
                              + reds[64 + row] * __expf(mw2 - gm)
                              + reds[96 + row] * __expf(mw3 - gm);
                    // all-masked row -> gm=-1e9 -> inv=0 -> exact zeros (double masking)
                    float inv = (gm < -5e8f) ? 0.f : __expf(rmax[mt][r] - gm) / tot;
                    #pragma unroll
                    for (int nt = 0; nt < 4; nt++) {
                        int col = w * 64 + nt * 16 + lr;
                        if (col < 224)
                            sP[row * 232 + col] = f2b(accS[mt][nt][r] * inv);
                    }
                }
            }
        }
        __syncthreads();

        // O = P @ V ; all waves; keys truncated exactly at 32(qt+1)
        f32x4 accO[2] = {};
        #pragma unroll
        for (int ks2 = 0; ks2 < 7; ks2++) {
            if (ks2 <= qt) {
                #pragma unroll
                for (int mt = 0; mt < 2; mt++) {
                    short8 afp = *(const short8*)(sP + (mt * 16 + lr) * 232 + ks2 * 32 + lq * 8);
                    accO[mt] = __builtin_amdgcn_mfma_f32_16x16x32_bf16(afp, bfv[ks2], accO[mt], 0, 0, 0);
                }
            }
        }
        #pragma unroll
        for (int mt = 0; mt < 2; mt++) {
            #pragma unroll
            for (int r = 0; r < 4; r++) {
                int row = q0 + mt * 16 + lq * 4 + r;
                if (row < LL)
                    og[(size_t)row * DD + w * 16 + lr] = accO[mt][r];
            }
        }
        // no end-of-qtile barrier: next qtile's redm/sP writes are already ordered
        // after barriers that all waves (incl. these PV reads) must pass first
    }
}

extern "C" void kernel_launch(void* const* d_in, const int* in_sizes, int n_in,
                              void* d_out, int out_size, void* d_ws, size_t ws_size,
                              hipStream_t stream) {
    const int* log_seqs = (const int*)d_in[0];
    const float* seqs_embs = (const float*)d_in[1];
    const int* entire = (const int*)d_in[2];
    const float* Wq = (const float*)d_in[3];
    const float* bq = (const float*)d_in[4];
    const float* Wk = (const float*)d_in[5];
    const float* bk = (const float*)d_in[6];
    const float* Wv = (const float*)d_in[7];
    const float* bv = (const float*)d_in[8];
    const float* lag = (const float*)d_in[9];
    const float* lab = (const float*)d_in[10];
    const float* lfg = (const float*)d_in[11];
    const float* lfb = (const float*)d_in[12];
    const float* W1 = (const float*)d_in[13];
    const float* b1 = (const float*)d_in[14];
    const float* W2 = (const float*)d_in[15];
    const float* b2 = (const float*)d_in[16];
    const float* llg = (const float*)d_in[17];
    const float* llb = (const float*)d_in[18];
    float* out = (float*)d_out;
    float* ws = (float*)d_ws;

    // workspace ~246 MB (262.45 MB proven safe)
    const size_t n = (size_t)BL * DD;
    float* tgt = ws;
    float* aout = ws + n;
    ushort_t* srcb = (ushort_t*)(ws + 2 * n);
    ushort_t* qb = srcb + n;
    ushort_t* kb = qb + n;
    ushort_t* lnb = kb + n;          // dedicated: read by gemm_qkv z=0 while z writes qb/kb/vt
    ushort_t* WqkvT = lnb + n;
    ushort_t* W1T = WqkvT + (size_t)NBLK * 3 * DD * DD;
    ushort_t* W2T = W1T + (size_t)NBLK * DD * DD;
    float* keepf = (float*)(W2T + (size_t)NBLK * DD * DD);
    float* kmf = keepf + BL;
    ushort_t* vt = (ushort_t*)(kmf + BL);   // [BB*HH*DK][LLP] bf16 V^T (30.4 MB)
    ushort_t* hb = qb;               // FFN1 out: qb dead after attention

    mask_kernel<<<(BL + 255) / 256, 256, 0, stream>>>(log_seqs, entire, keepf, kmf);
    prep_kernel<<<BL, 256, 0, stream>>>(log_seqs, seqs_embs, tgt, srcb);
    dim3 tw(16, 16, 10);
    wtrans10_kernel<<<tw, 256, 0, stream>>>(Wq, Wk, Wv, W1, W2, WqkvT, W1T, W2T);
    vtail_kernel<<<(BB * HH * DK * 8 + 255) / 256, 256, 0, stream>>>(vt);

    dim3 gg(BL / 128, DD / 128);
    dim3 gq(BL / 128, DD / 128, 3);
    for (int i = 0; i < NBLK; i++) {
        size_t wo = (size_t)i * DD * DD;
        // lnb = bf16(LN(tgt, ln_attn))
        ln_kernel<<<BL, 128, 0, stream>>>(tgt, nullptr, nullptr, lnb,
                                          lag + i * DD, lab + i * DD, nullptr);
        // fused q,k,v projections -> qb,kb (bf16) + vt (bf16, transposed, pitch 232)
        gemm_qkv<<<gq, 256, 0, stream>>>(lnb, srcb, WqkvT + (size_t)i * 3 * DD * DD,
                                         bq + i * DD, bk + i * DD, bv + i * DD, qb, vt);
        // attention (MFMA) -> aout fp32
        attn8_kernel<<<BB * HH, 256, 0, stream>>>(qb, kb, vt, kmf, aout);
        // tgt = LN(aout (+tgt)), bf16 copy to lnb
        ln_kernel<<<BL, 128, 0, stream>>>(aout, (i == 0) ? nullptr : tgt, tgt, lnb,
                                          lfg + i * DD, lfb + i * DD, nullptr);
        // hb = bf16(relu(lnb @ W1 + b1))
        gemm_mfma<<<gg, 256, 0, stream>>>(lnb, W1T + wo, b1 + i * DD, nullptr, hb,
                                          nullptr, 1, BL, DD, DD);
        // tgt = (tgt + hb @ W2 + b2) * keep
        gemm_mfma<<<gg, 256, 0, stream>>>(hb, W2T + wo, b2 + i * DD, tgt, nullptr,
                                          keepf, 2, BL, DD, DD);
    }
    ln_kernel<<<BL, 128, 0, stream>>>(tgt, nullptr, out, nullptr, llg, llb, keepf);
}